// Round 1
// baseline (1269.049 us; speedup 1.0000x reference)
//
#include <hip/hip_runtime.h>
#include <math.h>

#define BB_ 8
#define CC_ 256
#define LL_ 2048
#define HEADS_ 4
#define DHEAD_ 32
#define HID_ 128
#define EPS_ 1e-5f
#define SCALE_ 0.17677669529663687f   // 32^-0.5

// ---------------------------------------------------------------------------
// Kernel 1: fused channel-LayerNorm + QKV projection.
// Block = 256 threads, tile = 32 sequence positions of one batch.
// Stages x[b, 0:256, l0:l0+32] in LDS (coalesced: 32 contiguous floats/row),
// computes per-column mean/rstd, normalizes in place, then 384 output rows
// (q128|k128|v128) x 32 columns of dot-256.
// Writes q,k,v in [B, H, L, 32] layout for the attention kernel.
// ---------------------------------------------------------------------------
__global__ __launch_bounds__(256) void k_ln_qkv(
    const float* __restrict__ x, const float* __restrict__ g, const float* __restrict__ bvec,
    const float* __restrict__ Wq, const float* __restrict__ Wk, const float* __restrict__ Wv,
    float* __restrict__ q, float* __restrict__ k, float* __restrict__ v)
{
    __shared__ float xn[CC_ * 33];      // [c][l_sub], pad 33 to break bank conflicts
    __shared__ float cmean[32], crstd[32];
    const int b   = blockIdx.y;
    const int l0  = blockIdx.x * 32;
    const int tid = threadIdx.x;

    // stage raw x tile (coalesced 128B per 32-lane group)
    for (int idx = tid; idx < CC_ * 32; idx += 256) {
        int c = idx >> 5, ls = idx & 31;
        xn[c * 33 + ls] = x[((size_t)b * CC_ + c) * LL_ + l0 + ls];
    }
    __syncthreads();

    // per-column stats (32 threads, one column each; bank-free via pad)
    if (tid < 32) {
        float s = 0.f, s2 = 0.f;
        for (int c = 0; c < CC_; ++c) { float t = xn[c * 33 + tid]; s += t; s2 += t * t; }
        float mean = s * (1.f / CC_);
        float var  = s2 * (1.f / CC_) - mean * mean;
        cmean[tid] = mean;
        crstd[tid] = rsqrtf(var + EPS_);
    }
    __syncthreads();

    // normalize in place
    for (int idx = tid; idx < CC_ * 32; idx += 256) {
        int c = idx >> 5, ls = idx & 31;
        xn[c * 33 + ls] = (xn[c * 33 + ls] - cmean[ls]) * crstd[ls] * g[c] + bvec[c];
    }
    __syncthreads();

    // 384 outputs x 32 columns; 32 consecutive threads share one weight row
    // (global weight load is a wave-wide broadcast), LDS reads conflict-free.
    for (int idx = tid; idx < 384 * 32; idx += 256) {
        int o = idx >> 5, ls = idx & 31;
        const float* w; float* dst; int oo;
        if (o < 128)      { w = Wq; oo = o;       dst = q; }
        else if (o < 256) { w = Wk; oo = o - 128; dst = k; }
        else              { w = Wv; oo = o - 256; dst = v; }
        const float* wr = w + oo * CC_;
        float acc = 0.f;
        #pragma unroll 8
        for (int c = 0; c < CC_; ++c) acc += wr[c] * xn[c * 33 + ls];
        int h = oo >> 5, d = oo & 31;
        dst[(((size_t)b * HEADS_ + h) * LL_ + l0 + ls) * DHEAD_ + d] = acc;
    }
}

// ---------------------------------------------------------------------------
// Kernel 2: flash-style attention, online softmax.
// Block = 256 threads (4 waves), handles 32 queries of one (b,h).
// K/V streamed in 128-key LDS tiles; each wave owns 8 queries.
// Scores: lane j handles keys j and j+64 (dot-32 from LDS, padded rows).
// PV: p goes through per-wave LDS row; lane = (d, parity) accumulates.
// ---------------------------------------------------------------------------
__global__ __launch_bounds__(256) void k_attn(
    const float* __restrict__ q, const float* __restrict__ k, const float* __restrict__ v,
    float* __restrict__ ao)
{
    __shared__ float Qs[32 * 33];
    __shared__ float Ks[128 * 33];
    __shared__ float Vs[128 * 33];
    __shared__ float accO[32 * 33];
    __shared__ float pl[4 * 128];
    __shared__ float mrun[32], lrun[32];

    const int b = blockIdx.z, h = blockIdx.y;
    const int q0 = blockIdx.x * 32;
    const int tid = threadIdx.x;
    const int wave = tid >> 6, lane = tid & 63;
    const size_t base = ((size_t)b * HEADS_ + h) * LL_;   // row base in [BH, L, 32]

    for (int idx = tid; idx < 32 * 32; idx += 256) {
        int r = idx >> 5, d = idx & 31;
        Qs[r * 33 + d]  = q[(base + q0 + r) * DHEAD_ + d];
        accO[r * 33 + d] = 0.f;
    }
    if (tid < 32) { mrun[tid] = -INFINITY; lrun[tid] = 0.f; }

    for (int kt = 0; kt < LL_ / 128; ++kt) {
        __syncthreads();   // protect Ks/Vs from previous tile's readers
        const float* ksrc = k + (base + kt * 128) * DHEAD_;
        const float* vsrc = v + (base + kt * 128) * DHEAD_;
        for (int idx = tid; idx < 128 * 32; idx += 256) {
            int r = idx >> 5, d = idx & 31;
            Ks[r * 33 + d] = ksrc[idx];
            Vs[r * 33 + d] = vsrc[idx];
        }
        __syncthreads();

        for (int qq = 0; qq < 8; ++qq) {
            const int ql = wave * 8 + qq;          // local query row, per-wave disjoint
            const float* qrow = Qs + ql * 33;
            const float* k0 = Ks + lane * 33;
            const float* k1 = Ks + (lane + 64) * 33;
            float s0 = 0.f, s1 = 0.f;
            #pragma unroll
            for (int d = 0; d < DHEAD_; ++d) {
                float qd = qrow[d];
                s0 += qd * k0[d];
                s1 += qd * k1[d];
            }
            s0 *= SCALE_; s1 *= SCALE_;

            float tmax = fmaxf(s0, s1);
            #pragma unroll
            for (int off = 32; off; off >>= 1)
                tmax = fmaxf(tmax, __shfl_xor(tmax, off, 64));
            float mold = mrun[ql];
            float mnew = fmaxf(mold, tmax);
            float alpha = __expf(mold - mnew);     // exp(-inf)=0 handles first tile
            float p0 = __expf(s0 - mnew), p1 = __expf(s1 - mnew);
            float ps = p0 + p1;
            #pragma unroll
            for (int off = 32; off; off >>= 1)
                ps += __shfl_xor(ps, off, 64);

            pl[wave * 128 + lane]      = p0;       // key j = lane
            pl[wave * 128 + 64 + lane] = p1;       // key j = lane+64
            if (lane == 0) { mrun[ql] = mnew; lrun[ql] = lrun[ql] * alpha + ps; }

            // PV: lane -> (d = lane&31, parity = lane>>5); wave-synchronous LDS
            const int d = lane & 31, par = lane >> 5;
            float part = 0.f;
            #pragma unroll 8
            for (int t = 0; t < 64; ++t) {
                int j = 2 * t + par;
                part += pl[wave * 128 + j] * Vs[j * 33 + d];
            }
            part += __shfl_xor(part, 32, 64);
            if (lane < 32) accO[ql * 33 + d] = accO[ql * 33 + d] * alpha + part;
        }
    }
    __syncthreads();

    // write out in [B, L, HIDDEN] layout (hidden = h*32 + d)
    for (int idx = tid; idx < 32 * 32; idx += 256) {
        int r = idx >> 5, d = idx & 31;
        ao[((size_t)b * LL_ + q0 + r) * HID_ + h * DHEAD_ + d] = accO[r * 33 + d] / lrun[r];
    }
}

// ---------------------------------------------------------------------------
// Kernel 3: output projection (128->256) + bias + residual.
// Block = 256 threads, tile = 32 positions; ao tile staged in LDS.
// 32 consecutive threads share one Wo row (broadcast loads); writes coalesced.
// ---------------------------------------------------------------------------
__global__ __launch_bounds__(256) void k_oproj(
    const float* __restrict__ ao, const float* __restrict__ Wo, const float* __restrict__ bo,
    const float* __restrict__ x, float* __restrict__ out)
{
    __shared__ float at[32 * 129];
    const int b = blockIdx.y;
    const int l0 = blockIdx.x * 32;
    const int tid = threadIdx.x;

    const float* src = ao + ((size_t)b * LL_ + l0) * HID_;
    for (int idx = tid; idx < 32 * HID_; idx += 256) {
        int ls = idx >> 7, kk = idx & 127;
        at[ls * 129 + kk] = src[idx];
    }
    __syncthreads();

    for (int idx = tid; idx < CC_ * 32; idx += 256) {
        int o = idx >> 5, ls = idx & 31;
        const float* wr = Wo + o * HID_;
        const float* ar = at + ls * 129;
        float acc = 0.f;
        #pragma unroll 8
        for (int kk = 0; kk < HID_; ++kk) acc += wr[kk] * ar[kk];
        size_t oi = ((size_t)b * CC_ + o) * LL_ + l0 + ls;
        out[oi] = acc + bo[o] + x[oi];
    }
}

extern "C" void kernel_launch(void* const* d_in, const int* in_sizes, int n_in,
                              void* d_out, int out_size, void* d_ws, size_t ws_size,
                              hipStream_t stream) {
    const float* x  = (const float*)d_in[0];
    const float* g  = (const float*)d_in[1];
    const float* bv = (const float*)d_in[2];
    const float* Wq = (const float*)d_in[3];
    const float* Wk = (const float*)d_in[4];
    const float* Wv = (const float*)d_in[5];
    const float* Wo = (const float*)d_in[6];
    const float* bo = (const float*)d_in[7];
    float* out = (float*)d_out;

    const size_t qkv_elems = (size_t)BB_ * HEADS_ * LL_ * DHEAD_;   // 2M each
    float* q  = (float*)d_ws;
    float* k  = q + qkv_elems;
    float* v  = k + qkv_elems;
    float* ao = v + qkv_elems;            // [B, L, 128], 2M elems; total ws = 32 MB

    dim3 blk(256);
    k_ln_qkv<<<dim3(LL_ / 32, BB_), blk, 0, stream>>>(x, g, bv, Wq, Wk, Wv, q, k, v);
    k_attn <<<dim3(LL_ / 32, HEADS_, BB_), blk, 0, stream>>>(q, k, v, ao);
    k_oproj<<<dim3(LL_ / 32, BB_), blk, 0, stream>>>(ao, Wo, bo, x, out);
}

// Round 2
// 511.872 us; speedup vs baseline: 2.4792x; 2.4792x over previous
//
#include <hip/hip_runtime.h>
#include <math.h>

#define BB_ 8
#define CC_ 256
#define LL_ 2048
#define HEADS_ 4
#define DHEAD_ 32
#define HID_ 128
#define EPS_ 1e-5f
#define SCALE_ 0.17677669529663687f   // 32^-0.5

typedef short v8s __attribute__((ext_vector_type(8)));   // 8 bf16 (4 VGPRs) MFMA A/B frag
typedef float v4f __attribute__((ext_vector_type(4)));   // 4 fp32 MFMA C/D frag

__device__ inline short f2bf(float x) {   // RNE f32 -> bf16 bits
    union { float f; unsigned u; } a; a.f = x;
    unsigned r = a.u + 0x7fffu + ((a.u >> 16) & 1u);
    return (short)(r >> 16);
}

// ---------------------------------------------------------------------------
// Kernel 1: fused channel-LayerNorm + QKV projection (fp32 math).
// Emits bf16: q,k in [B*H, L, 32]; v TRANSPOSED in [B*H, 32, L] so the
// attention kernel can read MFMA B-fragments for V directly from global.
// ---------------------------------------------------------------------------
__global__ __launch_bounds__(256) void k_ln_qkv(
    const float* __restrict__ x, const float* __restrict__ g, const float* __restrict__ bvec,
    const float* __restrict__ Wq, const float* __restrict__ Wk, const float* __restrict__ Wv,
    short* __restrict__ q, short* __restrict__ k, short* __restrict__ v)
{
    __shared__ float xn[CC_ * 33];      // [c][l_sub], pad 33 to break bank conflicts
    __shared__ float cmean[32], crstd[32];
    const int b   = blockIdx.y;
    const int l0  = blockIdx.x * 32;
    const int tid = threadIdx.x;

    for (int idx = tid; idx < CC_ * 32; idx += 256) {
        int c = idx >> 5, ls = idx & 31;
        xn[c * 33 + ls] = x[((size_t)b * CC_ + c) * LL_ + l0 + ls];
    }
    __syncthreads();

    if (tid < 32) {
        float s = 0.f, s2 = 0.f;
        for (int c = 0; c < CC_; ++c) { float t = xn[c * 33 + tid]; s += t; s2 += t * t; }
        float mean = s * (1.f / CC_);
        float var  = s2 * (1.f / CC_) - mean * mean;
        cmean[tid] = mean;
        crstd[tid] = rsqrtf(var + EPS_);
    }
    __syncthreads();

    for (int idx = tid; idx < CC_ * 32; idx += 256) {
        int c = idx >> 5, ls = idx & 31;
        xn[c * 33 + ls] = (xn[c * 33 + ls] - cmean[ls]) * crstd[ls] * g[c] + bvec[c];
    }
    __syncthreads();

    for (int idx = tid; idx < 384 * 32; idx += 256) {
        int o = idx >> 5, ls = idx & 31;
        const float* w; int oo; int which;
        if (o < 128)      { w = Wq; oo = o;       which = 0; }
        else if (o < 256) { w = Wk; oo = o - 128; which = 1; }
        else              { w = Wv; oo = o - 256; which = 2; }
        const float* wr = w + oo * CC_;
        float acc = 0.f;
        #pragma unroll 8
        for (int c = 0; c < CC_; ++c) acc += wr[c] * xn[c * 33 + ls];
        int h = oo >> 5, d = oo & 31;
        size_t bh = (size_t)b * HEADS_ + h;
        short val = f2bf(acc);
        if (which == 0)      q[(bh * LL_ + l0 + ls) * DHEAD_ + d] = val;
        else if (which == 1) k[(bh * LL_ + l0 + ls) * DHEAD_ + d] = val;
        else                 v[(bh * DHEAD_ + d) * LL_ + l0 + ls] = val;   // transposed
    }
}

// ---------------------------------------------------------------------------
// Kernel 2: flash attention with bf16 MFMA (16x16x32), barrier-free.
// Block = 4 waves; wave w owns 16 q-rows. Per 128-key tile:
//   8 score MFMAs (Q frag held in regs all along, K frags from global),
//   log2-domain online softmax (quad-local shfl reductions),
//   P: C-layout -> per-wave LDS (stride 136 bf16) -> A-layout ds_read_b128,
//   8 PV MFMAs (V frags from transposed global layout).
// ---------------------------------------------------------------------------
__global__ __launch_bounds__(256) void k_attn(
    const short* __restrict__ q, const short* __restrict__ k, const short* __restrict__ v,
    float* __restrict__ ao)
{
    __shared__ short Pa[4][16 * 136];         // per-wave; row stride 136 bf16 (16B-aligned rows)
    const int bh   = blockIdx.y;              // b*HEADS + h
    const int b    = bh >> 2, h = bh & 3;
    const int tid  = threadIdx.x;
    const int wave = tid >> 6, lane = tid & 63;
    const int n    = lane & 15, quad = lane >> 4;
    const size_t kvbase = (size_t)bh * LL_ * DHEAD_;   // q,k: [bh][l][32]
    const size_t vbase  = (size_t)bh * DHEAD_ * LL_;   // v:   [bh][d][L]

    const int qrow = blockIdx.x * 64 + wave * 16 + n;  // A-operand row (m = lane&15)
    const v8s qf = *(const v8s*)(q + kvbase + (size_t)qrow * DHEAD_ + quad * 8);

    v4f O0 = {0.f,0.f,0.f,0.f}, O1 = {0.f,0.f,0.f,0.f};
    float mrow[4] = {-INFINITY,-INFINITY,-INFINITY,-INFINITY};
    float lrow[4] = {0.f,0.f,0.f,0.f};
    const float K1 = SCALE_ * 1.44269504088896f;       // fold softmax into exp2 domain
    short* pw = Pa[wave];

    for (int kt0 = 0; kt0 < LL_; kt0 += 128) {
        // ---- scores: 8 tiles of 16 keys, K-dim 32 in one MFMA each ----
        v4f S[8];
        #pragma unroll
        for (int t = 0; t < 8; ++t) {
            const v8s kf = *(const v8s*)(k + kvbase + (size_t)(kt0 + t * 16 + n) * DHEAD_ + quad * 8);
            S[t] = __builtin_amdgcn_mfma_f32_16x16x32_bf16(qf, kf, (v4f){0.f,0.f,0.f,0.f}, 0, 0, 0);
        }
        // ---- online softmax (row = quad*4+r, col = lane&15 per tile) ----
        float mnewv[4], alpha[4], psum[4];
        #pragma unroll
        for (int r = 0; r < 4; ++r) {
            float mx = S[0][r];
            #pragma unroll
            for (int t = 1; t < 8; ++t) mx = fmaxf(mx, S[t][r]);
            #pragma unroll
            for (int off = 1; off < 16; off <<= 1) mx = fmaxf(mx, __shfl_xor(mx, off, 64));
            float mt = mx * K1;                       // scaled, log2 domain
            float mn = fmaxf(mrow[r], mt);
            alpha[r] = exp2f(mrow[r] - mn);           // exp2(-inf)=0 on first tile
            mrow[r] = mn; mnewv[r] = mn; psum[r] = 0.f;
        }
        #pragma unroll
        for (int t = 0; t < 8; ++t) {
            #pragma unroll
            for (int r = 0; r < 4; ++r) {
                float p = exp2f(S[t][r] * K1 - mnewv[r]);
                psum[r] += p;
                pw[(quad * 4 + r) * 136 + t * 16 + n] = f2bf(p);   // C->A transpose via LDS
            }
        }
        #pragma unroll
        for (int r = 0; r < 4; ++r) {
            float ps = psum[r];
            #pragma unroll
            for (int off = 1; off < 16; off <<= 1) ps += __shfl_xor(ps, off, 64);
            lrow[r] = lrow[r] * alpha[r] + ps;
            O0[r] *= alpha[r]; O1[r] *= alpha[r];
        }
        // ---- PV: O[16q x 32d] += P[16q x 128k] * V[128k x 32d] ----
        #pragma unroll
        for (int kt = 0; kt < 4; ++kt) {
            const v8s pf  = *(const v8s*)(pw + n * 136 + kt * 32 + quad * 8);
            const v8s vf0 = *(const v8s*)(v + vbase + (size_t)n        * LL_ + kt0 + kt * 32 + quad * 8);
            const v8s vf1 = *(const v8s*)(v + vbase + (size_t)(n + 16) * LL_ + kt0 + kt * 32 + quad * 8);
            O0 = __builtin_amdgcn_mfma_f32_16x16x32_bf16(pf, vf0, O0, 0, 0, 0);
            O1 = __builtin_amdgcn_mfma_f32_16x16x32_bf16(pf, vf1, O1, 0, 0, 0);
        }
    }
    // ---- epilogue: rows quad*4+r, cols lane&15 (+16); ao is [B, L, 128] fp32 ----
    #pragma unroll
    for (int r = 0; r < 4; ++r) {
        float inv = 1.f / lrow[r];
        int row = blockIdx.x * 64 + wave * 16 + quad * 4 + r;
        float* dst = ao + ((size_t)b * LL_ + row) * HID_ + h * DHEAD_;
        dst[n]      = O0[r] * inv;
        dst[n + 16] = O1[r] * inv;
    }
}

// ---------------------------------------------------------------------------
// Kernel 3: output projection (128->256) + bias + residual (unchanged).
// ---------------------------------------------------------------------------
__global__ __launch_bounds__(256) void k_oproj(
    const float* __restrict__ ao, const float* __restrict__ Wo, const float* __restrict__ bo,
    const float* __restrict__ x, float* __restrict__ out)
{
    __shared__ float at[32 * 129];
    const int b = blockIdx.y;
    const int l0 = blockIdx.x * 32;
    const int tid = threadIdx.x;

    const float* src = ao + ((size_t)b * LL_ + l0) * HID_;
    for (int idx = tid; idx < 32 * HID_; idx += 256) {
        int ls = idx >> 7, kk = idx & 127;
        at[ls * 129 + kk] = src[idx];
    }
    __syncthreads();

    for (int idx = tid; idx < CC_ * 32; idx += 256) {
        int o = idx >> 5, ls = idx & 31;
        const float* wr = Wo + o * HID_;
        const float* ar = at + ls * 129;
        float acc = 0.f;
        #pragma unroll 8
        for (int kk = 0; kk < HID_; ++kk) acc += wr[kk] * ar[kk];
        size_t oi = ((size_t)b * CC_ + o) * LL_ + l0 + ls;
        out[oi] = acc + bo[o] + x[oi];
    }
}

extern "C" void kernel_launch(void* const* d_in, const int* in_sizes, int n_in,
                              void* d_out, int out_size, void* d_ws, size_t ws_size,
                              hipStream_t stream) {
    const float* x  = (const float*)d_in[0];
    const float* g  = (const float*)d_in[1];
    const float* bv = (const float*)d_in[2];
    const float* Wq = (const float*)d_in[3];
    const float* Wk = (const float*)d_in[4];
    const float* Wv = (const float*)d_in[5];
    const float* Wo = (const float*)d_in[6];
    const float* bo = (const float*)d_in[7];
    float* out = (float*)d_out;

    const size_t qkv_elems = (size_t)BB_ * HEADS_ * LL_ * DHEAD_;   // 2M bf16 each
    short* q  = (short*)d_ws;
    short* k  = q + qkv_elems;
    short* v  = k + qkv_elems;
    float* ao = (float*)((char*)d_ws + 3 * qkv_elems * sizeof(short)); // [B, L, 128] fp32, 8 MB

    dim3 blk(256);
    k_ln_qkv<<<dim3(LL_ / 32, BB_), blk, 0, stream>>>(x, g, bv, Wq, Wk, Wv, q, k, v);
    k_attn <<<dim3(LL_ / 64, BB_ * HEADS_), blk, 0, stream>>>(q, k, v, ao);
    k_oproj<<<dim3(LL_ / 32, BB_), blk, 0, stream>>>(ao, Wo, bo, x, out);
}

// Round 3
// 242.216 us; speedup vs baseline: 5.2393x; 2.1133x over previous
//
#include <hip/hip_runtime.h>
#include <math.h>

#define BB_ 8
#define CC_ 256
#define LL_ 2048
#define HEADS_ 4
#define DHEAD_ 32
#define HID_ 128
#define EPS_ 1e-5f
#define SCALE_ 0.17677669529663687f   // 32^-0.5

typedef short v8s __attribute__((ext_vector_type(8)));   // 8 bf16 (4 VGPRs) MFMA A/B frag
typedef float v4f __attribute__((ext_vector_type(4)));   // 4 fp32 MFMA C/D frag

__device__ inline short f2bf(float x) {   // RNE f32 -> bf16 bits
    union { float f; unsigned u; } a; a.f = x;
    unsigned r = a.u + 0x7fffu + ((a.u >> 16) & 1u);
    return (short)(r >> 16);
}

// ---------------------------------------------------------------------------
// Kernel 0: weight prep — fp32 -> bf16. wqkv[384][256] (q|k|v), wo[256][128].
// ---------------------------------------------------------------------------
__global__ __launch_bounds__(256) void k_prep(
    const float* __restrict__ Wq, const float* __restrict__ Wk, const float* __restrict__ Wv,
    const float* __restrict__ Wo, short* __restrict__ wqkv, short* __restrict__ wo)
{
    int idx = blockIdx.x * 256 + threadIdx.x;
    if (idx < 384 * 256) {
        int o = idx >> 8, c = idx & 255;
        float s;
        if (o < 128)      s = Wq[o * 256 + c];
        else if (o < 256) s = Wk[(o - 128) * 256 + c];
        else              s = Wv[(o - 256) * 256 + c];
        wqkv[idx] = f2bf(s);
    } else {
        int i2 = idx - 384 * 256;      // 256*128 Wo elems
        wo[i2] = f2bf(Wo[i2]);
    }
}

// ---------------------------------------------------------------------------
// Kernel 1: channel-LayerNorm + QKV projection via MFMA.
// Block: (b, 32 l-positions). Stage x [256c][32l] fp32 (pad 33) -> stats ->
// normalize+transpose into bf16 xnT [32l][264] (A-operand layout) -> GEMM:
// wave w: rows (w>>1)*16, cols (w&1)*192..+191; K=256 in 8 MFMA steps.
// q,k out: [B*H, L, 32] bf16; v out transposed: [B*H, 32, L] bf16.
// ---------------------------------------------------------------------------
__global__ __launch_bounds__(256) void k_ln_qkv(
    const float* __restrict__ x, const float* __restrict__ g, const float* __restrict__ bvec,
    const short* __restrict__ wqkv,
    short* __restrict__ q, short* __restrict__ k, short* __restrict__ v)
{
    __shared__ float xn[CC_ * 33];
    __shared__ short xnT[32 * 264];
    __shared__ float ps_[8 * 32], ps2_[8 * 32];
    __shared__ float cmean[32], crstd[32];
    const int b   = blockIdx.y;
    const int l0  = blockIdx.x * 32;
    const int tid = threadIdx.x;

    // stage (coalesced reads; LDS writes 2-way = free)
    for (int idx = tid; idx < CC_ * 32; idx += 256) {
        int c = idx >> 5, ls = idx & 31;
        xn[c * 33 + ls] = x[((size_t)b * CC_ + c) * LL_ + l0 + ls];
    }
    __syncthreads();

    // stats: 8 partials x 32 cols
    {
        int part = tid >> 5, col = tid & 31;
        float s = 0.f, s2 = 0.f;
        #pragma unroll
        for (int cc = 0; cc < 32; ++cc) {
            float t = xn[(part * 32 + cc) * 33 + col];
            s += t; s2 += t * t;
        }
        ps_[part * 32 + col] = s; ps2_[part * 32 + col] = s2;
    }
    __syncthreads();
    if (tid < 32) {
        float s = 0.f, s2 = 0.f;
        #pragma unroll
        for (int p = 0; p < 8; ++p) { s += ps_[p * 32 + tid]; s2 += ps2_[p * 32 + tid]; }
        float mean = s * (1.f / CC_);
        float var  = s2 * (1.f / CC_) - mean * mean;
        cmean[tid] = mean;
        crstd[tid] = rsqrtf(var + EPS_);
    }
    __syncthreads();

    // normalize + transpose to bf16 A-layout (packed u32 writes, conflict-free)
    for (int idx = tid; idx < 32 * 128; idx += 256) {
        int ls = idx >> 7, cc = idx & 127;
        int c0 = 2 * cc, c1 = 2 * cc + 1;
        float mu = cmean[ls], rs = crstd[ls];
        float a0 = (xn[c0 * 33 + ls] - mu) * rs * g[c0] + bvec[c0];
        float a1 = (xn[c1 * 33 + ls] - mu) * rs * g[c1] + bvec[c1];
        unsigned pk = (unsigned short)f2bf(a0) | ((unsigned)(unsigned short)f2bf(a1) << 16);
        *(unsigned*)(xnT + ls * 264 + c0) = pk;
    }
    __syncthreads();

    // MFMA GEMM: [32 l] x [384 o], K=256
    const int wave = tid >> 6, lane = tid & 63;
    const int n = lane & 15, quad = lane >> 4;
    const int rowbase = (wave >> 1) * 16;
    const int colbase = (wave & 1) * 192;

    v4f acc[12];
    #pragma unroll
    for (int ct = 0; ct < 12; ++ct) acc[ct] = (v4f){0.f, 0.f, 0.f, 0.f};

    #pragma unroll
    for (int ks = 0; ks < 8; ++ks) {
        const v8s af = *(const v8s*)(xnT + (rowbase + n) * 264 + ks * 32 + quad * 8);
        #pragma unroll
        for (int ct = 0; ct < 12; ++ct) {
            const v8s bfrag = *(const v8s*)(wqkv + (size_t)(colbase + ct * 16 + n) * 256 + ks * 32 + quad * 8);
            acc[ct] = __builtin_amdgcn_mfma_f32_16x16x32_bf16(af, bfrag, acc[ct], 0, 0, 0);
        }
    }

    // scatter: D row = quad*4+r -> l, col = n -> o
    #pragma unroll
    for (int ct = 0; ct < 12; ++ct) {
        int o = colbase + ct * 16 + n;
        int which = o >> 7, oo = o & 127;
        int h = oo >> 5, d = oo & 31;
        size_t bh = (size_t)b * HEADS_ + h;
        #pragma unroll
        for (int r = 0; r < 4; ++r) {
            int l = l0 + rowbase + quad * 4 + r;
            short val = f2bf(acc[ct][r]);
            if (which == 0)      q[(bh * LL_ + l) * DHEAD_ + d] = val;
            else if (which == 1) k[(bh * LL_ + l) * DHEAD_ + d] = val;
            else                 v[(bh * DHEAD_ + d) * LL_ + l] = val;
        }
    }
}

// ---------------------------------------------------------------------------
// Kernel 2: flash attention with bf16 MFMA (16x16x32), barrier-free.
// ---------------------------------------------------------------------------
__global__ __launch_bounds__(256) void k_attn(
    const short* __restrict__ q, const short* __restrict__ k, const short* __restrict__ v,
    short* __restrict__ ao)
{
    __shared__ short Pa[4][16 * 136];
    const int bh   = blockIdx.y;
    const int b    = bh >> 2, h = bh & 3;
    const int tid  = threadIdx.x;
    const int wave = tid >> 6, lane = tid & 63;
    const int n    = lane & 15, quad = lane >> 4;
    const size_t kvbase = (size_t)bh * LL_ * DHEAD_;
    const size_t vbase  = (size_t)bh * DHEAD_ * LL_;

    const int qrow = blockIdx.x * 64 + wave * 16 + n;
    const v8s qf = *(const v8s*)(q + kvbase + (size_t)qrow * DHEAD_ + quad * 8);

    v4f O0 = {0.f,0.f,0.f,0.f}, O1 = {0.f,0.f,0.f,0.f};
    float mrow[4] = {-INFINITY,-INFINITY,-INFINITY,-INFINITY};
    float lrow[4] = {0.f,0.f,0.f,0.f};
    const float K1 = SCALE_ * 1.44269504088896f;
    short* pw = Pa[wave];

    for (int kt0 = 0; kt0 < LL_; kt0 += 128) {
        v4f S[8];
        #pragma unroll
        for (int t = 0; t < 8; ++t) {
            const v8s kf = *(const v8s*)(k + kvbase + (size_t)(kt0 + t * 16 + n) * DHEAD_ + quad * 8);
            S[t] = __builtin_amdgcn_mfma_f32_16x16x32_bf16(qf, kf, (v4f){0.f,0.f,0.f,0.f}, 0, 0, 0);
        }
        float mnewv[4], alpha[4], psum[4];
        #pragma unroll
        for (int r = 0; r < 4; ++r) {
            float mx = S[0][r];
            #pragma unroll
            for (int t = 1; t < 8; ++t) mx = fmaxf(mx, S[t][r]);
            #pragma unroll
            for (int off = 1; off < 16; off <<= 1) mx = fmaxf(mx, __shfl_xor(mx, off, 64));
            float mt = mx * K1;
            float mn = fmaxf(mrow[r], mt);
            alpha[r] = exp2f(mrow[r] - mn);
            mrow[r] = mn; mnewv[r] = mn; psum[r] = 0.f;
        }
        #pragma unroll
        for (int t = 0; t < 8; ++t) {
            #pragma unroll
            for (int r = 0; r < 4; ++r) {
                float p = exp2f(S[t][r] * K1 - mnewv[r]);
                psum[r] += p;
                pw[(quad * 4 + r) * 136 + t * 16 + n] = f2bf(p);
            }
        }
        #pragma unroll
        for (int r = 0; r < 4; ++r) {
            float ps = psum[r];
            #pragma unroll
            for (int off = 1; off < 16; off <<= 1) ps += __shfl_xor(ps, off, 64);
            lrow[r] = lrow[r] * alpha[r] + ps;
            O0[r] *= alpha[r]; O1[r] *= alpha[r];
        }
        #pragma unroll
        for (int kt = 0; kt < 4; ++kt) {
            const v8s pf  = *(const v8s*)(pw + n * 136 + kt * 32 + quad * 8);
            const v8s vf0 = *(const v8s*)(v + vbase + (size_t)n        * LL_ + kt0 + kt * 32 + quad * 8);
            const v8s vf1 = *(const v8s*)(v + vbase + (size_t)(n + 16) * LL_ + kt0 + kt * 32 + quad * 8);
            O0 = __builtin_amdgcn_mfma_f32_16x16x32_bf16(pf, vf0, O0, 0, 0, 0);
            O1 = __builtin_amdgcn_mfma_f32_16x16x32_bf16(pf, vf1, O1, 0, 0, 0);
        }
    }
    #pragma unroll
    for (int r = 0; r < 4; ++r) {
        float inv = 1.f / lrow[r];
        int row = blockIdx.x * 64 + wave * 16 + quad * 4 + r;
        short* dst = ao + ((size_t)b * LL_ + row) * HID_ + h * DHEAD_;
        dst[n]      = f2bf(O0[r] * inv);
        dst[n + 16] = f2bf(O1[r] * inv);
    }
}

// ---------------------------------------------------------------------------
// Kernel 3: output projection via MFMA + bias + residual. No LDS, no barriers.
// Block: (b, 64 l). Wave w: l-rows w*16..+15 as MFMA N; o = 256 as MFMA M.
// D[m=o][n=l] -> out[b][o][l] l-contiguous stores.
// ---------------------------------------------------------------------------
__global__ __launch_bounds__(256) void k_oproj(
    const short* __restrict__ ao, const short* __restrict__ wo, const float* __restrict__ bo,
    const float* __restrict__ x, float* __restrict__ out)
{
    const int b = blockIdx.y;
    const int l0 = blockIdx.x * 64;
    const int tid = threadIdx.x;
    const int wave = tid >> 6, lane = tid & 63;
    const int n = lane & 15, quad = lane >> 4;
    const int lsub = l0 + wave * 16;

    // B-frags: ao rows l = lsub + n, k = ks*32 + quad*8 (contiguous 16B)
    v8s bf[4];
    #pragma unroll
    for (int ks = 0; ks < 4; ++ks)
        bf[ks] = *(const v8s*)(ao + ((size_t)b * LL_ + lsub + n) * HID_ + ks * 32 + quad * 8);

    #pragma unroll
    for (int ot = 0; ot < 16; ++ot) {
        v4f acc = {0.f, 0.f, 0.f, 0.f};
        #pragma unroll
        for (int ks = 0; ks < 4; ++ks) {
            const v8s af = *(const v8s*)(wo + (size_t)(ot * 16 + n) * HID_ + ks * 32 + quad * 8);
            acc = __builtin_amdgcn_mfma_f32_16x16x32_bf16(af, bf[ks], acc, 0, 0, 0);
        }
        #pragma unroll
        for (int r = 0; r < 4; ++r) {
            int o = ot * 16 + quad * 4 + r;
            size_t oi = ((size_t)b * CC_ + o) * LL_ + lsub + n;
            out[oi] = acc[r] + bo[o] + x[oi];
        }
    }
}

extern "C" void kernel_launch(void* const* d_in, const int* in_sizes, int n_in,
                              void* d_out, int out_size, void* d_ws, size_t ws_size,
                              hipStream_t stream) {
    const float* x  = (const float*)d_in[0];
    const float* g  = (const float*)d_in[1];
    const float* bv = (const float*)d_in[2];
    const float* Wq = (const float*)d_in[3];
    const float* Wk = (const float*)d_in[4];
    const float* Wv = (const float*)d_in[5];
    const float* Wo = (const float*)d_in[6];
    const float* bo = (const float*)d_in[7];
    float* out = (float*)d_out;

    const size_t qkv_elems = (size_t)BB_ * HEADS_ * LL_ * DHEAD_;   // 2M
    short* q    = (short*)d_ws;
    short* k    = q + qkv_elems;
    short* v    = k + qkv_elems;
    short* ao   = v + qkv_elems;                 // [B, L, 128] bf16, 2M
    short* wqkv = ao + qkv_elems;                // 384*256
    short* wo   = wqkv + 384 * 256;              // 256*128

    dim3 blk(256);
    k_prep  <<<dim3((384 * 256 + 256 * 128) / 256), blk, 0, stream>>>(Wq, Wk, Wv, Wo, wqkv, wo);
    k_ln_qkv<<<dim3(LL_ / 32, BB_), blk, 0, stream>>>(x, g, bv, wqkv, q, k, v);
    k_attn  <<<dim3(LL_ / 64, BB_ * HEADS_), blk, 0, stream>>>(q, k, v, ao);
    k_oproj <<<dim3(LL_ / 64, BB_), blk, 0, stream>>>(ao, wo, bo, x, out);
}

// Round 5
// 230.955 us; speedup vs baseline: 5.4948x; 1.0488x over previous
//
#include <hip/hip_runtime.h>
#include <math.h>

#define BB_ 8
#define CC_ 256
#define LL_ 2048
#define HEADS_ 4
#define DHEAD_ 32
#define HID_ 128
#define EPS_ 1e-5f
#define SCALE_ 0.17677669529663687f   // 32^-0.5
#define K1_ (SCALE_ * 1.44269504088896f)   // folded into q at bf16-write time

typedef short v8s __attribute__((ext_vector_type(8)));
typedef short v4s __attribute__((ext_vector_type(4)));
typedef float v4f __attribute__((ext_vector_type(4)));

__device__ inline short f2bf(float x) {   // RNE f32 -> bf16 bits
    union { float f; unsigned u; } a; a.f = x;
    unsigned r = a.u + 0x7fffu + ((a.u >> 16) & 1u);
    return (short)(r >> 16);
}

// ---------------------------------------------------------------------------
// Kernel 0: weight prep — fp32 -> bf16. wqkv[384][256] (q|k|v), wo[256][128].
// ---------------------------------------------------------------------------
__global__ __launch_bounds__(256) void k_prep(
    const float* __restrict__ Wq, const float* __restrict__ Wk, const float* __restrict__ Wv,
    const float* __restrict__ Wo, short* __restrict__ wqkv, short* __restrict__ wo)
{
    int idx = blockIdx.x * 256 + threadIdx.x;
    if (idx < 384 * 256) {
        int o = idx >> 8, c = idx & 255;
        float s;
        if (o < 128)      s = Wq[o * 256 + c];
        else if (o < 256) s = Wk[(o - 128) * 256 + c];
        else              s = Wv[(o - 256) * 256 + c];
        wqkv[idx] = f2bf(s);
    } else {
        int i2 = idx - 384 * 256;
        wo[i2] = f2bf(Wo[i2]);
    }
}

// ---------------------------------------------------------------------------
// Kernel 1: channel-LayerNorm + QKV projection via MFMA.
// q is pre-scaled by SCALE*log2(e) so attention exp2 needs no multiply.
// q,k out: [B*H, L, 32] bf16; v out transposed: [B*H, 32, L] bf16.
// ---------------------------------------------------------------------------
__global__ __launch_bounds__(256) void k_ln_qkv(
    const float* __restrict__ x, const float* __restrict__ g, const float* __restrict__ bvec,
    const short* __restrict__ wqkv,
    short* __restrict__ q, short* __restrict__ k, short* __restrict__ v)
{
    __shared__ float xn[CC_ * 33];
    __shared__ short xnT[32 * 264];
    __shared__ float ps_[8 * 32], ps2_[8 * 32];
    __shared__ float cmean[32], crstd[32];
    const int b   = blockIdx.y;
    const int l0  = blockIdx.x * 32;
    const int tid = threadIdx.x;

    for (int idx = tid; idx < CC_ * 32; idx += 256) {
        int c = idx >> 5, ls = idx & 31;
        xn[c * 33 + ls] = x[((size_t)b * CC_ + c) * LL_ + l0 + ls];
    }
    __syncthreads();

    {
        int part = tid >> 5, col = tid & 31;
        float s = 0.f, s2 = 0.f;
        #pragma unroll
        for (int cc = 0; cc < 32; ++cc) {
            float t = xn[(part * 32 + cc) * 33 + col];
            s += t; s2 += t * t;
        }
        ps_[part * 32 + col] = s; ps2_[part * 32 + col] = s2;
    }
    __syncthreads();
    if (tid < 32) {
        float s = 0.f, s2 = 0.f;
        #pragma unroll
        for (int p = 0; p < 8; ++p) { s += ps_[p * 32 + tid]; s2 += ps2_[p * 32 + tid]; }
        float mean = s * (1.f / CC_);
        float var  = s2 * (1.f / CC_) - mean * mean;
        cmean[tid] = mean;
        crstd[tid] = rsqrtf(var + EPS_);
    }
    __syncthreads();

    for (int idx = tid; idx < 32 * 128; idx += 256) {
        int ls = idx >> 7, cc = idx & 127;
        int c0 = 2 * cc, c1 = 2 * cc + 1;
        float mu = cmean[ls], rs = crstd[ls];
        float a0 = (xn[c0 * 33 + ls] - mu) * rs * g[c0] + bvec[c0];
        float a1 = (xn[c1 * 33 + ls] - mu) * rs * g[c1] + bvec[c1];
        // same-element-type (short) paired store; __syncthreads below orders it
        xnT[ls * 264 + c0]     = f2bf(a0);
        xnT[ls * 264 + c0 + 1] = f2bf(a1);
    }
    __syncthreads();

    const int wave = tid >> 6, lane = tid & 63;
    const int n = lane & 15, quad = lane >> 4;
    const int rowbase = (wave >> 1) * 16;
    const int colbase = (wave & 1) * 192;

    v4f acc[12];
    #pragma unroll
    for (int ct = 0; ct < 12; ++ct) acc[ct] = (v4f){0.f, 0.f, 0.f, 0.f};

    #pragma unroll
    for (int ks = 0; ks < 8; ++ks) {
        const v8s af = *(const v8s*)(xnT + (rowbase + n) * 264 + ks * 32 + quad * 8);
        #pragma unroll
        for (int ct = 0; ct < 12; ++ct) {
            const v8s bfrag = *(const v8s*)(wqkv + (size_t)(colbase + ct * 16 + n) * 256 + ks * 32 + quad * 8);
            acc[ct] = __builtin_amdgcn_mfma_f32_16x16x32_bf16(af, bfrag, acc[ct], 0, 0, 0);
        }
    }

    #pragma unroll
    for (int ct = 0; ct < 12; ++ct) {
        int o = colbase + ct * 16 + n;
        int which = o >> 7, oo = o & 127;
        int h = oo >> 5, d = oo & 31;
        size_t bh = (size_t)b * HEADS_ + h;
        #pragma unroll
        for (int r = 0; r < 4; ++r) {
            int l = l0 + rowbase + quad * 4 + r;
            if (which == 0)      q[(bh * LL_ + l) * DHEAD_ + d] = f2bf(acc[ct][r] * K1_);
            else if (which == 1) k[(bh * LL_ + l) * DHEAD_ + d] = f2bf(acc[ct][r]);
            else                 v[(bh * DHEAD_ + d) * LL_ + l] = f2bf(acc[ct][r]);
        }
    }
}

// ---------------------------------------------------------------------------
// Kernel 2: flash attention, S^T formulation, no max-subtraction.
// mfma(kf, qf) -> S^T: lane (n,quad) holds scores for q-row n at keys
// 16t+4quad+r -> P rows are lane-local contiguous: short4 LDS stores.
// Explicit lgkmcnt(0) fence between P-write and PV-read phases (cross-lane
// RAW through LDS; same-type stores keep TBAA honest, fence keeps HW honest).
// No per-tile reductions; denominator reduced once after the K-loop.
// ---------------------------------------------------------------------------
#define PSTR_ 136   // halves per P row: 272B row stride, 16B-aligned reads, 2-way banks
__global__ __launch_bounds__(256) void k_attn(
    const short* __restrict__ q, const short* __restrict__ k, const short* __restrict__ v,
    short* __restrict__ ao)
{
    __shared__ short Pa[4][16 * PSTR_];
    const int bh   = blockIdx.y;
    const int b    = bh >> 2, h = bh & 3;
    const int tid  = threadIdx.x;
    const int wave = tid >> 6, lane = tid & 63;
    const int n    = lane & 15, quad = lane >> 4;
    const size_t kvbase = (size_t)bh * LL_ * DHEAD_;
    const size_t vbase  = (size_t)bh * DHEAD_ * LL_;

    const int qrow = blockIdx.x * 64 + wave * 16 + n;
    const v8s qf = *(const v8s*)(q + kvbase + (size_t)qrow * DHEAD_ + quad * 8);

    v4f O0 = {0.f,0.f,0.f,0.f}, O1 = {0.f,0.f,0.f,0.f};
    float psum = 0.f;                     // denominator partial for q-row n
    short* pw = Pa[wave];

    for (int kt0 = 0; kt0 < LL_; kt0 += 128) {
        // scores (transposed): S[t] holds q-row n, keys kt0 + 16t + 4*quad + r
        v4f S[8];
        #pragma unroll
        for (int t = 0; t < 8; ++t) {
            const v8s kf = *(const v8s*)(k + kvbase + (size_t)(kt0 + t * 16 + n) * DHEAD_ + quad * 8);
            S[t] = __builtin_amdgcn_mfma_f32_16x16x32_bf16(kf, qf, (v4f){0.f,0.f,0.f,0.f}, 0, 0, 0);
        }
        // p = exp2(S) (q pre-scaled); 4 contiguous bf16 -> one 8B LDS store
        #pragma unroll
        for (int t = 0; t < 8; ++t) {
            float p0 = exp2f(S[t][0]), p1 = exp2f(S[t][1]);
            float p2 = exp2f(S[t][2]), p3 = exp2f(S[t][3]);
            psum += (p0 + p1) + (p2 + p3);
            v4s pk = { f2bf(p0), f2bf(p1), f2bf(p2), f2bf(p3) };
            *(v4s*)(pw + n * PSTR_ + t * 16 + quad * 4) = pk;
        }
        // cross-lane RAW: all wave LDS writes must land before fragment reads
        asm volatile("s_waitcnt lgkmcnt(0)" ::: "memory");
        // PV: O[16q x 32d] += P[16q x 128k] * V[128k x 32d]
        #pragma unroll
        for (int kt = 0; kt < 4; ++kt) {
            const v8s pf  = *(const v8s*)(pw + n * PSTR_ + kt * 32 + quad * 8);
            const v8s vf0 = *(const v8s*)(v + vbase + (size_t)n        * LL_ + kt0 + kt * 32 + quad * 8);
            const v8s vf1 = *(const v8s*)(v + vbase + (size_t)(n + 16) * LL_ + kt0 + kt * 32 + quad * 8);
            O0 = __builtin_amdgcn_mfma_f32_16x16x32_bf16(pf, vf0, O0, 0, 0, 0);
            O1 = __builtin_amdgcn_mfma_f32_16x16x32_bf16(pf, vf1, O1, 0, 0, 0);
        }
        // WAR: keep next tile's P writes from hoisting above this tile's reads
        asm volatile("" ::: "memory");
    }
    // denominator: lanes {n, n+16, n+32, n+48} hold disjoint k-partials of q-row n
    psum += __shfl_xor(psum, 16, 64);
    psum += __shfl_xor(psum, 32, 64);
    // O rows are q-local quad*4+r -> fetch that row's denominator from lane quad*4+r
    #pragma unroll
    for (int r = 0; r < 4; ++r) {
        float inv = 1.f / __shfl(psum, quad * 4 + r, 64);
        int row = blockIdx.x * 64 + wave * 16 + quad * 4 + r;
        short* dst = ao + ((size_t)b * LL_ + row) * HID_ + h * DHEAD_;
        dst[n]      = f2bf(O0[r] * inv);
        dst[n + 16] = f2bf(O1[r] * inv);
    }
}

// ---------------------------------------------------------------------------
// Kernel 3: output projection via MFMA + bias + residual. No LDS, no barriers.
// ---------------------------------------------------------------------------
__global__ __launch_bounds__(256) void k_oproj(
    const short* __restrict__ ao, const short* __restrict__ wo, const float* __restrict__ bo,
    const float* __restrict__ x, float* __restrict__ out)
{
    const int b = blockIdx.y;
    const int l0 = blockIdx.x * 64;
    const int tid = threadIdx.x;
    const int wave = tid >> 6, lane = tid & 63;
    const int n = lane & 15, quad = lane >> 4;
    const int lsub = l0 + wave * 16;

    v8s bf[4];
    #pragma unroll
    for (int ks = 0; ks < 4; ++ks)
        bf[ks] = *(const v8s*)(ao + ((size_t)b * LL_ + lsub + n) * HID_ + ks * 32 + quad * 8);

    #pragma unroll
    for (int ot = 0; ot < 16; ++ot) {
        v4f acc = {0.f, 0.f, 0.f, 0.f};
        #pragma unroll
        for (int ks = 0; ks < 4; ++ks) {
            const v8s af = *(const v8s*)(wo + (size_t)(ot * 16 + n) * HID_ + ks * 32 + quad * 8);
            acc = __builtin_amdgcn_mfma_f32_16x16x32_bf16(af, bf[ks], acc, 0, 0, 0);
        }
        #pragma unroll
        for (int r = 0; r < 4; ++r) {
            int o = ot * 16 + quad * 4 + r;
            size_t oi = ((size_t)b * CC_ + o) * LL_ + lsub + n;
            out[oi] = acc[r] + bo[o] + x[oi];
        }
    }
}

extern "C" void kernel_launch(void* const* d_in, const int* in_sizes, int n_in,
                              void* d_out, int out_size, void* d_ws, size_t ws_size,
                              hipStream_t stream) {
    const float* x  = (const float*)d_in[0];
    const float* g  = (const float*)d_in[1];
    const float* bv = (const float*)d_in[2];
    const float* Wq = (const float*)d_in[3];
    const float* Wk = (const float*)d_in[4];
    const float* Wv = (const float*)d_in[5];
    const float* Wo = (const float*)d_in[6];
    const float* bo = (const float*)d_in[7];
    float* out = (float*)d_out;

    const size_t qkv_elems = (size_t)BB_ * HEADS_ * LL_ * DHEAD_;
    short* q    = (short*)d_ws;
    short* k    = q + qkv_elems;
    short* v    = k + qkv_elems;
    short* ao   = v + qkv_elems;
    short* wqkv = ao + qkv_elems;
    short* wo   = wqkv + 384 * 256;

    dim3 blk(256);
    k_prep  <<<dim3((384 * 256 + 256 * 128) / 256), blk, 0, stream>>>(Wq, Wk, Wv, Wo, wqkv, wo);
    k_ln_qkv<<<dim3(LL_ / 32, BB_), blk, 0, stream>>>(x, g, bv, wqkv, q, k, v);
    k_attn  <<<dim3(LL_ / 64, BB_ * HEADS_), blk, 0, stream>>>(q, k, v, ao);
    k_oproj <<<dim3(LL_ / 64, BB_), blk, 0, stream>>>(ao, wo, bo, x, out);
}

// Round 6
// 224.723 us; speedup vs baseline: 5.6472x; 1.0277x over previous
//
#include <hip/hip_runtime.h>
#include <math.h>

#define BB_ 8
#define CC_ 256
#define LL_ 2048
#define HEADS_ 4
#define DHEAD_ 32
#define HID_ 128
#define EPS_ 1e-5f
#define SCALE_ 0.17677669529663687f   // 32^-0.5
#define K1_ (SCALE_ * 1.44269504088896f)   // folded into q at bf16-write time

typedef short v8s __attribute__((ext_vector_type(8)));
typedef short v4s __attribute__((ext_vector_type(4)));
typedef float v4f __attribute__((ext_vector_type(4)));
typedef unsigned v2u __attribute__((ext_vector_type(2)));

__device__ inline short f2bf(float x) {   // RNE f32 -> bf16 bits
    union { float f; unsigned u; } a; a.f = x;
    unsigned r = a.u + 0x7fffu + ((a.u >> 16) & 1u);
    return (short)(r >> 16);
}
__device__ inline unsigned fbits(float x) { union { float f; unsigned u; } a; a.f = x; return a.u; }

// ---------------------------------------------------------------------------
// Kernel 0: weight prep — fp32 -> bf16. wqkv[384][256] (q|k|v), wo[256][128].
// ---------------------------------------------------------------------------
__global__ __launch_bounds__(256) void k_prep(
    const float* __restrict__ Wq, const float* __restrict__ Wk, const float* __restrict__ Wv,
    const float* __restrict__ Wo, short* __restrict__ wqkv, short* __restrict__ wo)
{
    int idx = blockIdx.x * 256 + threadIdx.x;
    if (idx < 384 * 256) {
        int o = idx >> 8, c = idx & 255;
        float s;
        if (o < 128)      s = Wq[o * 256 + c];
        else if (o < 256) s = Wk[(o - 128) * 256 + c];
        else              s = Wv[(o - 256) * 256 + c];
        wqkv[idx] = f2bf(s);
    } else {
        int i2 = idx - 384 * 256;
        wo[i2] = f2bf(Wo[i2]);
    }
}

// ---------------------------------------------------------------------------
// Kernel 1: channel-LayerNorm + QKV projection via MFMA.
// Epilogue: MFMA results scattered to LDS staging, then fully-coalesced
// 16B/lane global writes (q,k contiguous 1KB/wave; v in 64B segments).
// q pre-scaled by SCALE*log2(e). q,k: [B*H, L, 32]; v: [B*H, 32, L] bf16.
// ---------------------------------------------------------------------------
__global__ __launch_bounds__(256) void k_ln_qkv(
    const float* __restrict__ x, const float* __restrict__ g, const float* __restrict__ bvec,
    const short* __restrict__ wqkv,
    short* __restrict__ q, short* __restrict__ k, short* __restrict__ v)
{
    __shared__ float xn[CC_ * 33];
    __shared__ short xnT[32 * 264];      // normalized input, later reused as q|k staging
    __shared__ short st2[128 * 48];      // v staging: [o'][l], stride 48 (96B, 16B-mult)
    __shared__ float ps_[8 * 32], ps2_[8 * 32];
    __shared__ float cmean[32], crstd[32];
    const int b   = blockIdx.y;
    const int l0  = blockIdx.x * 32;
    const int tid = threadIdx.x;

    for (int idx = tid; idx < CC_ * 32; idx += 256) {
        int c = idx >> 5, ls = idx & 31;
        xn[c * 33 + ls] = x[((size_t)b * CC_ + c) * LL_ + l0 + ls];
    }
    __syncthreads();

    {
        int part = tid >> 5, col = tid & 31;
        float s = 0.f, s2 = 0.f;
        #pragma unroll
        for (int cc = 0; cc < 32; ++cc) {
            float t = xn[(part * 32 + cc) * 33 + col];
            s += t; s2 += t * t;
        }
        ps_[part * 32 + col] = s; ps2_[part * 32 + col] = s2;
    }
    __syncthreads();
    if (tid < 32) {
        float s = 0.f, s2 = 0.f;
        #pragma unroll
        for (int p = 0; p < 8; ++p) { s += ps_[p * 32 + tid]; s2 += ps2_[p * 32 + tid]; }
        float mean = s * (1.f / CC_);
        float var  = s2 * (1.f / CC_) - mean * mean;
        cmean[tid] = mean;
        crstd[tid] = rsqrtf(var + EPS_);
    }
    __syncthreads();

    for (int idx = tid; idx < 32 * 128; idx += 256) {
        int ls = idx >> 7, cc = idx & 127;
        int c0 = 2 * cc, c1 = 2 * cc + 1;
        float mu = cmean[ls], rs = crstd[ls];
        float a0 = (xn[c0 * 33 + ls] - mu) * rs * g[c0] + bvec[c0];
        float a1 = (xn[c1 * 33 + ls] - mu) * rs * g[c1] + bvec[c1];
        xnT[ls * 264 + c0]     = f2bf(a0);
        xnT[ls * 264 + c0 + 1] = f2bf(a1);
    }
    __syncthreads();

    const int wave = tid >> 6, lane = tid & 63;
    const int n = lane & 15, quad = lane >> 4;
    const int rowbase = (wave >> 1) * 16;
    const int colbase = (wave & 1) * 192;

    v4f acc[12];
    #pragma unroll
    for (int ct = 0; ct < 12; ++ct) acc[ct] = (v4f){0.f, 0.f, 0.f, 0.f};

    #pragma unroll
    for (int ks = 0; ks < 8; ++ks) {
        const v8s af = *(const v8s*)(xnT + (rowbase + n) * 264 + ks * 32 + quad * 8);
        #pragma unroll
        for (int ct = 0; ct < 12; ++ct) {
            const v8s bfrag = *(const v8s*)(wqkv + (size_t)(colbase + ct * 16 + n) * 256 + ks * 32 + quad * 8);
            acc[ct] = __builtin_amdgcn_mfma_f32_16x16x32_bf16(af, bfrag, acc[ct], 0, 0, 0);
        }
    }
    __syncthreads();   // all waves done reading xnT; safe to reuse as staging

    // scatter results to LDS: q|k -> xnT[l][o(0..255)], v -> st2[o-256][l]
    #pragma unroll
    for (int ct = 0; ct < 12; ++ct) {
        int o = colbase + ct * 16 + n;
        #pragma unroll
        for (int r = 0; r < 4; ++r) {
            int l = rowbase + quad * 4 + r;
            float val = acc[ct][r];
            if (o < 128)      xnT[l * 264 + o] = f2bf(val * K1_);
            else if (o < 256) xnT[l * 264 + o] = f2bf(val);
            else              st2[(o - 256) * 48 + l] = f2bf(val);
        }
    }
    __syncthreads();

    // coalesced writes: q,k 16B/lane fully contiguous per wave
    for (int u = tid; u < 512; u += 256) {
        int h = u >> 7, rest = u & 127;
        int l = rest >> 2, dg = rest & 3;
        size_t bh = (size_t)b * HEADS_ + h;
        v8s qv = *(const v8s*)(xnT + l * 264 + h * 32 + dg * 8);
        *(v8s*)(q + (bh * LL_ + l0 + l) * DHEAD_ + dg * 8) = qv;
        v8s kv = *(const v8s*)(xnT + l * 264 + 128 + h * 32 + dg * 8);
        *(v8s*)(k + (bh * LL_ + l0 + l) * DHEAD_ + dg * 8) = kv;
    }
    for (int u = tid; u < 512; u += 256) {
        int op = u >> 2, lg = u & 3;               // op = h*32+d
        v8s vv = *(const v8s*)(st2 + op * 48 + lg * 8);
        int h = op >> 5, d = op & 31;
        *(v8s*)(v + (((size_t)b * HEADS_ + h) * DHEAD_ + d) * LL_ + l0 + lg * 8) = vv;
    }
}

// ---------------------------------------------------------------------------
// Kernel 2: flash attention, S^T formulation, no max-subtraction.
// Software-pipelined: V frags (this tile) + K frags (next tile) issued before
// the exp/pack VALU phase so global latency overlaps compute. P transpose via
// XOR-swizzled LDS (granule^=(n&7)): write b64 and read b128 both uniform
// minimum-cycle, zero bank conflicts. Pack = +0x8000 half-up + v_perm.
// ---------------------------------------------------------------------------
#define PSTR_ 128
__global__ __launch_bounds__(256) void k_attn(
    const short* __restrict__ q, const short* __restrict__ k, const short* __restrict__ v,
    short* __restrict__ ao)
{
    __shared__ short Pa[4][16 * PSTR_];
    const int bh   = blockIdx.y;
    const int b    = bh >> 2, h = bh & 3;
    const int tid  = threadIdx.x;
    const int wave = tid >> 6, lane = tid & 63;
    const int n    = lane & 15, quad = lane >> 4;
    const int swz  = (n & 7) << 4;                 // granule swizzle (halves)
    const size_t kvbase = (size_t)bh * LL_ * DHEAD_;
    const size_t vbase  = (size_t)bh * DHEAD_ * LL_;

    const int qrow = blockIdx.x * 64 + wave * 16 + n;
    const v8s qf = *(const v8s*)(q + kvbase + (size_t)qrow * DHEAD_ + quad * 8);

    v4f O0 = {0.f,0.f,0.f,0.f}, O1 = {0.f,0.f,0.f,0.f};
    float psum = 0.f;
    short* pw = Pa[wave];

    // preload K frags for tile 0
    v8s kf[8];
    #pragma unroll
    for (int t = 0; t < 8; ++t)
        kf[t] = *(const v8s*)(k + kvbase + (size_t)(t * 16 + n) * DHEAD_ + quad * 8);

    for (int kt0 = 0; kt0 < LL_; kt0 += 128) {
        // scores (transposed): S[t] holds q-row n, keys kt0 + 16t + 4*quad + r
        v4f S[8];
        #pragma unroll
        for (int t = 0; t < 8; ++t)
            S[t] = __builtin_amdgcn_mfma_f32_16x16x32_bf16(kf[t], qf, (v4f){0.f,0.f,0.f,0.f}, 0, 0, 0);

        // prefetch: V frags for this tile, K frags for next tile (overlap w/ VALU)
        v8s vf[8];
        #pragma unroll
        for (int kt = 0; kt < 4; ++kt) {
            vf[2*kt]   = *(const v8s*)(v + vbase + (size_t)n        * LL_ + kt0 + kt * 32 + quad * 8);
            vf[2*kt+1] = *(const v8s*)(v + vbase + (size_t)(n + 16) * LL_ + kt0 + kt * 32 + quad * 8);
        }
        if (kt0 + 128 < LL_) {
            #pragma unroll
            for (int t = 0; t < 8; ++t)
                kf[t] = *(const v8s*)(k + kvbase + (size_t)(kt0 + 128 + t * 16 + n) * DHEAD_ + quad * 8);
        }

        // p = exp2(S) (q pre-scaled); half-up bf16 pack; swizzled b64 store
        #pragma unroll
        for (int t = 0; t < 8; ++t) {
            float p0 = __builtin_amdgcn_exp2f(S[t][0]);
            float p1 = __builtin_amdgcn_exp2f(S[t][1]);
            float p2 = __builtin_amdgcn_exp2f(S[t][2]);
            float p3 = __builtin_amdgcn_exp2f(S[t][3]);
            psum += (p0 + p1) + (p2 + p3);
            unsigned lo = __builtin_amdgcn_perm(fbits(p1) + 0x8000u, fbits(p0) + 0x8000u, 0x07060302u);
            unsigned hi = __builtin_amdgcn_perm(fbits(p3) + 0x8000u, fbits(p2) + 0x8000u, 0x07060302u);
            v2u pk2 = { lo, hi };
            *(v4s*)(pw + n * PSTR_ + ((t * 16 + quad * 4) ^ swz)) = __builtin_bit_cast(v4s, pk2);
        }
        // cross-lane RAW through LDS: drain wave's writes, pin compiler order
        asm volatile("s_waitcnt lgkmcnt(0)" ::: "memory");
        // PV: O[16q x 32d] += P[16q x 128k] * V[128k x 32d]
        #pragma unroll
        for (int kt = 0; kt < 4; ++kt) {
            const v8s pf = *(const v8s*)(pw + n * PSTR_ + ((kt * 32 + quad * 8) ^ swz));
            O0 = __builtin_amdgcn_mfma_f32_16x16x32_bf16(pf, vf[2*kt],   O0, 0, 0, 0);
            O1 = __builtin_amdgcn_mfma_f32_16x16x32_bf16(pf, vf[2*kt+1], O1, 0, 0, 0);
        }
        // WAR: next tile's P writes must not hoist above this tile's P reads
        asm volatile("" ::: "memory");
    }
    // denominator: lanes {n, n+16, n+32, n+48} hold disjoint k-partials of q-row n
    psum += __shfl_xor(psum, 16, 64);
    psum += __shfl_xor(psum, 32, 64);
    #pragma unroll
    for (int r = 0; r < 4; ++r) {
        float inv = 1.f / __shfl(psum, quad * 4 + r, 64);
        int row = blockIdx.x * 64 + wave * 16 + quad * 4 + r;
        short* dst = ao + ((size_t)b * LL_ + row) * HID_ + h * DHEAD_;
        dst[n]      = f2bf(O0[r] * inv);
        dst[n + 16] = f2bf(O1[r] * inv);
    }
}

// ---------------------------------------------------------------------------
// Kernel 3: output projection via MFMA + bias + residual. No LDS, no barriers.
// ---------------------------------------------------------------------------
__global__ __launch_bounds__(256) void k_oproj(
    const short* __restrict__ ao, const short* __restrict__ wo, const float* __restrict__ bo,
    const float* __restrict__ x, float* __restrict__ out)
{
    const int b = blockIdx.y;
    const int l0 = blockIdx.x * 64;
    const int tid = threadIdx.x;
    const int wave = tid >> 6, lane = tid & 63;
    const int n = lane & 15, quad = lane >> 4;
    const int lsub = l0 + wave * 16;

    v8s bf[4];
    #pragma unroll
    for (int ks = 0; ks < 4; ++ks)
        bf[ks] = *(const v8s*)(ao + ((size_t)b * LL_ + lsub + n) * HID_ + ks * 32 + quad * 8);

    #pragma unroll
    for (int ot = 0; ot < 16; ++ot) {
        v4f acc = {0.f, 0.f, 0.f, 0.f};
        #pragma unroll
        for (int ks = 0; ks < 4; ++ks) {
            const v8s af = *(const v8s*)(wo + (size_t)(ot * 16 + n) * HID_ + ks * 32 + quad * 8);
            acc = __builtin_amdgcn_mfma_f32_16x16x32_bf16(af, bf[ks], acc, 0, 0, 0);
        }
        #pragma unroll
        for (int r = 0; r < 4; ++r) {
            int o = ot * 16 + quad * 4 + r;
            size_t oi = ((size_t)b * CC_ + o) * LL_ + lsub + n;
            out[oi] = acc[r] + bo[o] + x[oi];
        }
    }
}

extern "C" void kernel_launch(void* const* d_in, const int* in_sizes, int n_in,
                              void* d_out, int out_size, void* d_ws, size_t ws_size,
                              hipStream_t stream) {
    const float* x  = (const float*)d_in[0];
    const float* g  = (const float*)d_in[1];
    const float* bv = (const float*)d_in[2];
    const float* Wq = (const float*)d_in[3];
    const float* Wk = (const float*)d_in[4];
    const float* Wv = (const float*)d_in[5];
    const float* Wo = (const float*)d_in[6];
    const float* bo = (const float*)d_in[7];
    float* out = (float*)d_out;

    const size_t qkv_elems = (size_t)BB_ * HEADS_ * LL_ * DHEAD_;
    short* q    = (short*)d_ws;
    short* k    = q + qkv_elems;
    short* v    = k + qkv_elems;
    short* ao   = v + qkv_elems;
    short* wqkv = ao + qkv_elems;
    short* wo   = wqkv + 384 * 256;

    dim3 blk(256);
    k_prep  <<<dim3((384 * 256 + 256 * 128) / 256), blk, 0, stream>>>(Wq, Wk, Wv, Wo, wqkv, wo);
    k_ln_qkv<<<dim3(LL_ / 32, BB_), blk, 0, stream>>>(x, g, bv, wqkv, q, k, v);
    k_attn  <<<dim3(LL_ / 64, BB_ * HEADS_), blk, 0, stream>>>(q, k, v, ao);
    k_oproj <<<dim3(LL_ / 64, BB_), blk, 0, stream>>>(ao, wo, bo, x, out);
}

// Round 7
// 185.989 us; speedup vs baseline: 6.8232x; 1.2083x over previous
//
#include <hip/hip_runtime.h>
#include <math.h>

#define BB_ 8
#define CC_ 256
#define LL_ 2048
#define HEADS_ 4
#define DHEAD_ 32
#define HID_ 128
#define EPS_ 1e-5f
#define SCALE_ 0.17677669529663687f   // 32^-0.5
#define K1_ (SCALE_ * 1.44269504088896f)   // folded into q at bf16-write time

typedef short v8s  __attribute__((ext_vector_type(8)));
typedef float v4f  __attribute__((ext_vector_type(4)));
typedef float v16f __attribute__((ext_vector_type(16)));
typedef unsigned v4u __attribute__((ext_vector_type(4)));

__device__ inline short f2bf(float x) {   // RNE f32 -> bf16 bits
    union { float f; unsigned u; } a; a.f = x;
    unsigned r = a.u + 0x7fffu + ((a.u >> 16) & 1u);
    return (short)(r >> 16);
}
__device__ inline unsigned fbits(float x) { union { float f; unsigned u; } a; a.f = x; return a.u; }

// ---------------------------------------------------------------------------
// Kernel 0: weight prep — fp32 -> bf16. wqkv[384][256] (q|k|v), wo[256][128].
// ---------------------------------------------------------------------------
__global__ __launch_bounds__(256) void k_prep(
    const float* __restrict__ Wq, const float* __restrict__ Wk, const float* __restrict__ Wv,
    const float* __restrict__ Wo, short* __restrict__ wqkv, short* __restrict__ wo)
{
    int idx = blockIdx.x * 256 + threadIdx.x;
    if (idx < 384 * 256) {
        int o = idx >> 8, c = idx & 255;
        float s;
        if (o < 128)      s = Wq[o * 256 + c];
        else if (o < 256) s = Wk[(o - 128) * 256 + c];
        else              s = Wv[(o - 256) * 256 + c];
        wqkv[idx] = f2bf(s);
    } else {
        int i2 = idx - 384 * 256;
        wo[i2] = f2bf(Wo[i2]);
    }
}

// ---------------------------------------------------------------------------
// Kernel 1: channel-LayerNorm + QKV projection via MFMA (unchanged r6).
// q pre-scaled by SCALE*log2(e). q,k: [B*H, L, 32]; v: [B*H, 32, L] bf16.
// ---------------------------------------------------------------------------
__global__ __launch_bounds__(256) void k_ln_qkv(
    const float* __restrict__ x, const float* __restrict__ g, const float* __restrict__ bvec,
    const short* __restrict__ wqkv,
    short* __restrict__ q, short* __restrict__ k, short* __restrict__ v)
{
    __shared__ float xn[CC_ * 33];
    __shared__ short xnT[32 * 264];
    __shared__ short st2[128 * 48];
    __shared__ float ps_[8 * 32], ps2_[8 * 32];
    __shared__ float cmean[32], crstd[32];
    const int b   = blockIdx.y;
    const int l0  = blockIdx.x * 32;
    const int tid = threadIdx.x;

    for (int idx = tid; idx < CC_ * 32; idx += 256) {
        int c = idx >> 5, ls = idx & 31;
        xn[c * 33 + ls] = x[((size_t)b * CC_ + c) * LL_ + l0 + ls];
    }
    __syncthreads();

    {
        int part = tid >> 5, col = tid & 31;
        float s = 0.f, s2 = 0.f;
        #pragma unroll
        for (int cc = 0; cc < 32; ++cc) {
            float t = xn[(part * 32 + cc) * 33 + col];
            s += t; s2 += t * t;
        }
        ps_[part * 32 + col] = s; ps2_[part * 32 + col] = s2;
    }
    __syncthreads();
    if (tid < 32) {
        float s = 0.f, s2 = 0.f;
        #pragma unroll
        for (int p = 0; p < 8; ++p) { s += ps_[p * 32 + tid]; s2 += ps2_[p * 32 + tid]; }
        float mean = s * (1.f / CC_);
        float var  = s2 * (1.f / CC_) - mean * mean;
        cmean[tid] = mean;
        crstd[tid] = rsqrtf(var + EPS_);
    }
    __syncthreads();

    for (int idx = tid; idx < 32 * 128; idx += 256) {
        int ls = idx >> 7, cc = idx & 127;
        int c0 = 2 * cc, c1 = 2 * cc + 1;
        float mu = cmean[ls], rs = crstd[ls];
        float a0 = (xn[c0 * 33 + ls] - mu) * rs * g[c0] + bvec[c0];
        float a1 = (xn[c1 * 33 + ls] - mu) * rs * g[c1] + bvec[c1];
        xnT[ls * 264 + c0]     = f2bf(a0);
        xnT[ls * 264 + c0 + 1] = f2bf(a1);
    }
    __syncthreads();

    const int wave = tid >> 6, lane = tid & 63;
    const int n = lane & 15, quad = lane >> 4;
    const int rowbase = (wave >> 1) * 16;
    const int colbase = (wave & 1) * 192;

    v4f acc[12];
    #pragma unroll
    for (int ct = 0; ct < 12; ++ct) acc[ct] = (v4f){0.f, 0.f, 0.f, 0.f};

    #pragma unroll
    for (int ks = 0; ks < 8; ++ks) {
        const v8s af = *(const v8s*)(xnT + (rowbase + n) * 264 + ks * 32 + quad * 8);
        #pragma unroll
        for (int ct = 0; ct < 12; ++ct) {
            const v8s bfrag = *(const v8s*)(wqkv + (size_t)(colbase + ct * 16 + n) * 256 + ks * 32 + quad * 8);
            acc[ct] = __builtin_amdgcn_mfma_f32_16x16x32_bf16(af, bfrag, acc[ct], 0, 0, 0);
        }
    }
    __syncthreads();

    #pragma unroll
    for (int ct = 0; ct < 12; ++ct) {
        int o = colbase + ct * 16 + n;
        #pragma unroll
        for (int r = 0; r < 4; ++r) {
            int l = rowbase + quad * 4 + r;
            float val = acc[ct][r];
            if (o < 128)      xnT[l * 264 + o] = f2bf(val * K1_);
            else if (o < 256) xnT[l * 264 + o] = f2bf(val);
            else              st2[(o - 256) * 48 + l] = f2bf(val);
        }
    }
    __syncthreads();

    for (int u = tid; u < 512; u += 256) {
        int h = u >> 7, rest = u & 127;
        int l = rest >> 2, dg = rest & 3;
        size_t bh = (size_t)b * HEADS_ + h;
        v8s qv = *(const v8s*)(xnT + l * 264 + h * 32 + dg * 8);
        *(v8s*)(q + (bh * LL_ + l0 + l) * DHEAD_ + dg * 8) = qv;
        v8s kv = *(const v8s*)(xnT + l * 264 + 128 + h * 32 + dg * 8);
        *(v8s*)(k + (bh * LL_ + l0 + l) * DHEAD_ + dg * 8) = kv;
    }
    for (int u = tid; u < 512; u += 256) {
        int op = u >> 2, lg = u & 3;
        v8s vv = *(const v8s*)(st2 + op * 48 + lg * 8);
        int h = op >> 5, d = op & 31;
        *(v8s*)(v + (((size_t)b * HEADS_ + h) * DHEAD_ + d) * LL_ + l0 + lg * 8) = vv;
    }
}

// ---------------------------------------------------------------------------
// Kernel 2: flash attention, 32x32x16 MFMA, S^T, no max-subtraction,
// NO LDS / NO barriers / NO fences. P relayout (C-layout -> A-layout) is
// in-register: same q lives in the same lane; only keys swap between lane
// pairs (q, q+32) via 8x shfl_xor(32) + per-half selects.
// Layouts (32x32x16): A[m=lane&31][k=(lane>>5)*8+j], B[k=(lane>>5)*8+j][n=lane&31],
// D col=lane&31, row=(reg&3)+8*(reg>>2)+4*(lane>>5).
// ---------------------------------------------------------------------------
__global__ __launch_bounds__(256) void k_attn(
    const short* __restrict__ q, const short* __restrict__ k, const short* __restrict__ v,
    short* __restrict__ ao)
{
    const int bh   = blockIdx.y;
    const int b    = bh >> 2, h = bh & 3;
    const int tid  = threadIdx.x;
    const int wave = tid >> 6, lane = tid & 63;
    const int m    = lane & 31;          // q for B/D roles, key for A role, d for V role
    const int half = lane >> 5;
    const size_t kvbase = (size_t)bh * LL_ * DHEAD_;   // q,k: [bh][l][32]
    const size_t vbase  = (size_t)bh * DHEAD_ * LL_;   // v:   [bh][d][L]

    const int q0 = blockIdx.x * 128 + wave * 32;

    // persistent Q B-frags: B[k=d][n=q], d = half*8+j (+16)
    const v8s qf0 = *(const v8s*)(q + kvbase + (size_t)(q0 + m) * DHEAD_ + half * 8);
    const v8s qf1 = *(const v8s*)(q + kvbase + (size_t)(q0 + m) * DHEAD_ + 16 + half * 8);

    v16f O = {};
    float psum = 0.f;

    // tile-0 operands
    v8s kf0 = *(const v8s*)(k + kvbase + (size_t)m * DHEAD_ + half * 8);
    v8s kf1 = *(const v8s*)(k + kvbase + (size_t)m * DHEAD_ + 16 + half * 8);
    v8s vf0 = *(const v8s*)(v + vbase + (size_t)m * LL_ + half * 8);
    v8s vf1 = *(const v8s*)(v + vbase + (size_t)m * LL_ + 16 + half * 8);

    for (int kt0 = 0; kt0 < LL_; kt0 += 32) {
        // scores: S^T[key][q] = sum_d K[key][d] * Q[q][d]  (q pre-scaled by K1)
        v16f S = __builtin_amdgcn_mfma_f32_32x32x16_bf16(kf0, qf0, (v16f){}, 0, 0, 0);
        S      = __builtin_amdgcn_mfma_f32_32x32x16_bf16(kf1, qf1, S,        0, 0, 0);

        // prefetch next tile (wrapped on last iter; harmless)
        const int ktn = (kt0 + 32) & (LL_ - 1);
        kf0 = *(const v8s*)(k + kvbase + (size_t)(ktn + m) * DHEAD_ + half * 8);
        kf1 = *(const v8s*)(k + kvbase + (size_t)(ktn + m) * DHEAD_ + 16 + half * 8);
        v8s vf0n = *(const v8s*)(v + vbase + (size_t)m * LL_ + ktn + half * 8);
        v8s vf1n = *(const v8s*)(v + vbase + (size_t)m * LL_ + ktn + 16 + half * 8);

        // p = exp2(S); pack key-pairs into dwords e0..e7 (bf16 half-up)
        unsigned e[8];
        #pragma unroll
        for (int i = 0; i < 8; ++i) {
            float pa = __builtin_amdgcn_exp2f(S[2 * i]);
            float pb = __builtin_amdgcn_exp2f(S[2 * i + 1]);
            psum += pa + pb;
            e[i] = __builtin_amdgcn_perm(fbits(pb) + 0x8000u, fbits(pa) + 0x8000u, 0x07060302u);
        }
        // exchange with lane^32 partner; assemble A-frags for keys 0-15 / 16-31
        unsigned o0 = __shfl_xor(e[0], 32, 64), o1 = __shfl_xor(e[1], 32, 64);
        unsigned o2 = __shfl_xor(e[2], 32, 64), o3 = __shfl_xor(e[3], 32, 64);
        unsigned o4 = __shfl_xor(e[4], 32, 64), o5 = __shfl_xor(e[5], 32, 64);
        unsigned o6 = __shfl_xor(e[6], 32, 64), o7 = __shfl_xor(e[7], 32, 64);
        v4u f1 = half ? (v4u){o2, o3, e[2], e[3]} : (v4u){e[0], e[1], o0, o1};
        v4u f2 = half ? (v4u){o6, o7, e[6], e[7]} : (v4u){e[4], e[5], o4, o5};

        // PV: O[q][d] += P[q][key] * V[key][d]
        O = __builtin_amdgcn_mfma_f32_32x32x16_bf16(__builtin_bit_cast(v8s, f1), vf0, O, 0, 0, 0);
        O = __builtin_amdgcn_mfma_f32_32x32x16_bf16(__builtin_bit_cast(v8s, f2), vf1, O, 0, 0, 0);

        vf0 = vf0n; vf1 = vf1n;
    }

    // denominator: lane m holds partial for q=m over its keys; halves combine
    psum += __shfl_xor(psum, 32, 64);
    float invden = 1.f / psum;           // lane m: 1/den(q = m), both halves

    // epilogue: O reg r -> q-row (r&3)+8*(r>>2)+4*half, col d = m
    #pragma unroll
    for (int r = 0; r < 16; ++r) {
        int qr = (r & 3) + 8 * (r >> 2) + 4 * half;
        float inv = __shfl(invden, qr, 64);
        int row = q0 + qr;
        ao[((size_t)b * LL_ + row) * HID_ + h * DHEAD_ + m] = f2bf(O[r] * inv);
    }
}

// ---------------------------------------------------------------------------
// Kernel 3: output projection via MFMA + bias + residual (unchanged r6).
// ---------------------------------------------------------------------------
__global__ __launch_bounds__(256) void k_oproj(
    const short* __restrict__ ao, const short* __restrict__ wo, const float* __restrict__ bo,
    const float* __restrict__ x, float* __restrict__ out)
{
    const int b = blockIdx.y;
    const int l0 = blockIdx.x * 64;
    const int tid = threadIdx.x;
    const int wave = tid >> 6, lane = tid & 63;
    const int n = lane & 15, quad = lane >> 4;
    const int lsub = l0 + wave * 16;

    v8s bf[4];
    #pragma unroll
    for (int ks = 0; ks < 4; ++ks)
        bf[ks] = *(const v8s*)(ao + ((size_t)b * LL_ + lsub + n) * HID_ + ks * 32 + quad * 8);

    #pragma unroll
    for (int ot = 0; ot < 16; ++ot) {
        v4f acc = {0.f, 0.f, 0.f, 0.f};
        #pragma unroll
        for (int ks = 0; ks < 4; ++ks) {
            const v8s af = *(const v8s*)(wo + (size_t)(ot * 16 + n) * HID_ + ks * 32 + quad * 8);
            acc = __builtin_amdgcn_mfma_f32_16x16x32_bf16(af, bf[ks], acc, 0, 0, 0);
        }
        #pragma unroll
        for (int r = 0; r < 4; ++r) {
            int o = ot * 16 + quad * 4 + r;
            size_t oi = ((size_t)b * CC_ + o) * LL_ + lsub + n;
            out[oi] = acc[r] + bo[o] + x[oi];
        }
    }
}

extern "C" void kernel_launch(void* const* d_in, const int* in_sizes, int n_in,
                              void* d_out, int out_size, void* d_ws, size_t ws_size,
                              hipStream_t stream) {
    const float* x  = (const float*)d_in[0];
    const float* g  = (const float*)d_in[1];
    const float* bv = (const float*)d_in[2];
    const float* Wq = (const float*)d_in[3];
    const float* Wk = (const float*)d_in[4];
    const float* Wv = (const float*)d_in[5];
    const float* Wo = (const float*)d_in[6];
    const float* bo = (const float*)d_in[7];
    float* out = (float*)d_out;

    const size_t qkv_elems = (size_t)BB_ * HEADS_ * LL_ * DHEAD_;
    short* q    = (short*)d_ws;
    short* k    = q + qkv_elems;
    short* v    = k + qkv_elems;
    short* ao   = v + qkv_elems;
    short* wqkv = ao + qkv_elems;
    short* wo   = wqkv + 384 * 256;

    dim3 blk(256);
    k_prep  <<<dim3((384 * 256 + 256 * 128) / 256), blk, 0, stream>>>(Wq, Wk, Wv, Wo, wqkv, wo);
    k_ln_qkv<<<dim3(LL_ / 32, BB_), blk, 0, stream>>>(x, g, bv, wqkv, q, k, v);
    k_attn  <<<dim3(LL_ / 128, BB_ * HEADS_), blk, 0, stream>>>(q, k, v, ao);
    k_oproj <<<dim3(LL_ / 64, BB_), blk, 0, stream>>>(ao, wo, bo, x, out);
}

// Round 8
// 174.541 us; speedup vs baseline: 7.2708x; 1.0656x over previous
//
#include <hip/hip_runtime.h>
#include <math.h>

#define BB_ 8
#define CC_ 256
#define LL_ 2048
#define HEADS_ 4
#define DHEAD_ 32
#define HID_ 128
#define EPS_ 1e-5f
#define SCALE_ 0.17677669529663687f   // 32^-0.5
#define K1_ (SCALE_ * 1.44269504088896f)   // folded into q at bf16-write time

typedef short v8s  __attribute__((ext_vector_type(8)));
typedef float v4f  __attribute__((ext_vector_type(4)));
typedef float v16f __attribute__((ext_vector_type(16)));
typedef unsigned v4u __attribute__((ext_vector_type(4)));

__device__ inline short f2bf(float x) {   // RNE f32 -> bf16 bits
    union { float f; unsigned u; } a; a.f = x;
    unsigned r = a.u + 0x7fffu + ((a.u >> 16) & 1u);
    return (short)(r >> 16);
}
__device__ inline unsigned fbits(float x) { union { float f; unsigned u; } a; a.f = x; return a.u; }

// ---------------------------------------------------------------------------
// Kernel 0: weight prep — fp32 -> bf16. wqkv[384][256] (q|k|v), wo[256][128].
// ---------------------------------------------------------------------------
__global__ __launch_bounds__(256) void k_prep(
    const float* __restrict__ Wq, const float* __restrict__ Wk, const float* __restrict__ Wv,
    const float* __restrict__ Wo, short* __restrict__ wqkv, short* __restrict__ wo)
{
    int idx = blockIdx.x * 256 + threadIdx.x;
    if (idx < 384 * 256) {
        int o = idx >> 8, c = idx & 255;
        float s;
        if (o < 128)      s = Wq[o * 256 + c];
        else if (o < 256) s = Wk[(o - 128) * 256 + c];
        else              s = Wv[(o - 256) * 256 + c];
        wqkv[idx] = f2bf(s);
    } else {
        int i2 = idx - 384 * 256;
        wo[i2] = f2bf(Wo[i2]);
    }
}

// ---------------------------------------------------------------------------
// Kernel 1: channel-LayerNorm + QKV projection via MFMA. 512 threads/block
// (8 waves: 2 row-groups x 4 col-groups of 96 outputs) for 4 waves/SIMD.
// q pre-scaled by SCALE*log2(e). q,k: [B*H, L, 32]; v: [B*H, 32, L] bf16.
// ---------------------------------------------------------------------------
__global__ __launch_bounds__(512) void k_ln_qkv(
    const float* __restrict__ x, const float* __restrict__ g, const float* __restrict__ bvec,
    const short* __restrict__ wqkv,
    short* __restrict__ q, short* __restrict__ k, short* __restrict__ v)
{
    __shared__ float xn[CC_ * 33];
    __shared__ short xnT[32 * 264];      // normalized bf16, later reused as q|k staging
    __shared__ short st2[128 * 48];      // v staging: [o'][l], stride 48
    __shared__ float ps_[16 * 32], ps2_[16 * 32];
    __shared__ float cmean[32], crstd[32];
    const int b   = blockIdx.y;
    const int l0  = blockIdx.x * 32;
    const int tid = threadIdx.x;

    for (int idx = tid; idx < CC_ * 32; idx += 512) {
        int c = idx >> 5, ls = idx & 31;
        xn[c * 33 + ls] = x[((size_t)b * CC_ + c) * LL_ + l0 + ls];
    }
    __syncthreads();

    {
        int part = tid >> 5, col = tid & 31;   // 16 partials x 32 cols
        float s = 0.f, s2 = 0.f;
        #pragma unroll
        for (int cc = 0; cc < 16; ++cc) {
            float t = xn[(part * 16 + cc) * 33 + col];
            s += t; s2 += t * t;
        }
        ps_[part * 32 + col] = s; ps2_[part * 32 + col] = s2;
    }
    __syncthreads();
    if (tid < 32) {
        float s = 0.f, s2 = 0.f;
        #pragma unroll
        for (int p = 0; p < 16; ++p) { s += ps_[p * 32 + tid]; s2 += ps2_[p * 32 + tid]; }
        float mean = s * (1.f / CC_);
        float var  = s2 * (1.f / CC_) - mean * mean;
        cmean[tid] = mean;
        crstd[tid] = rsqrtf(var + EPS_);
    }
    __syncthreads();

    for (int idx = tid; idx < 32 * 128; idx += 512) {
        int ls = idx >> 7, cc = idx & 127;
        int c0 = 2 * cc, c1 = 2 * cc + 1;
        float mu = cmean[ls], rs = crstd[ls];
        float a0 = (xn[c0 * 33 + ls] - mu) * rs * g[c0] + bvec[c0];
        float a1 = (xn[c1 * 33 + ls] - mu) * rs * g[c1] + bvec[c1];
        xnT[ls * 264 + c0]     = f2bf(a0);
        xnT[ls * 264 + c0 + 1] = f2bf(a1);
    }
    __syncthreads();

    const int wave = tid >> 6, lane = tid & 63;
    const int n = lane & 15, quad = lane >> 4;
    const int rowbase = (wave >> 2) * 16;       // 2 row-groups
    const int colbase = (wave & 3) * 96;        // 4 col-groups of 96

    v4f acc[6];
    #pragma unroll
    for (int ct = 0; ct < 6; ++ct) acc[ct] = (v4f){0.f, 0.f, 0.f, 0.f};

    #pragma unroll
    for (int ks = 0; ks < 8; ++ks) {
        const v8s af = *(const v8s*)(xnT + (rowbase + n) * 264 + ks * 32 + quad * 8);
        #pragma unroll
        for (int ct = 0; ct < 6; ++ct) {
            const v8s bfrag = *(const v8s*)(wqkv + (size_t)(colbase + ct * 16 + n) * 256 + ks * 32 + quad * 8);
            acc[ct] = __builtin_amdgcn_mfma_f32_16x16x32_bf16(af, bfrag, acc[ct], 0, 0, 0);
        }
    }
    __syncthreads();   // all waves done reading xnT; safe to reuse as staging

    #pragma unroll
    for (int ct = 0; ct < 6; ++ct) {
        int o = colbase + ct * 16 + n;
        #pragma unroll
        for (int r = 0; r < 4; ++r) {
            int l = rowbase + quad * 4 + r;
            float val = acc[ct][r];
            if (o < 128)      xnT[l * 264 + o] = f2bf(val * K1_);
            else if (o < 256) xnT[l * 264 + o] = f2bf(val);
            else              st2[(o - 256) * 48 + l] = f2bf(val);
        }
    }
    __syncthreads();

    {
        int u = tid;                     // 512 threads, one pass each
        int h = u >> 7, rest = u & 127;
        int l = rest >> 2, dg = rest & 3;
        size_t bh = (size_t)b * HEADS_ + h;
        v8s qv = *(const v8s*)(xnT + l * 264 + h * 32 + dg * 8);
        *(v8s*)(q + (bh * LL_ + l0 + l) * DHEAD_ + dg * 8) = qv;
        v8s kv = *(const v8s*)(xnT + l * 264 + 128 + h * 32 + dg * 8);
        *(v8s*)(k + (bh * LL_ + l0 + l) * DHEAD_ + dg * 8) = kv;

        int op = u >> 2, lg = u & 3;
        v8s vv = *(const v8s*)(st2 + op * 48 + lg * 8);
        int h2 = op >> 5, d = op & 31;
        *(v8s*)(v + (((size_t)b * HEADS_ + h2) * DHEAD_ + d) * LL_ + l0 + lg * 8) = vv;
    }
}

// ---------------------------------------------------------------------------
// Kernel 2: flash attention, 32x32x16 MFMA, S^T, no max-subtraction.
// 512 threads = 4 q-waves x 2 key-halves (partials are exactly additive:
// no running max). P relayout C->A via v_permlane32_swap (VALU; shfl
// fallback). End: key-half-1 waves dump O/psum to LDS, half-0 combine+store.
// ---------------------------------------------------------------------------
__global__ __launch_bounds__(512) void k_attn(
    const short* __restrict__ q, const short* __restrict__ k, const short* __restrict__ v,
    short* __restrict__ ao)
{
    __shared__ float Ost[4][32][32];     // [q-wave][q-row][d]
    __shared__ float psumst[4 * 32];
    const int bh   = blockIdx.y;
    const int b    = bh >> 2, h = bh & 3;
    const int tid  = threadIdx.x;
    const int wave = tid >> 6, lane = tid & 63;
    const int wq   = wave & 3;           // q-subtile
    const int kh   = wave >> 2;          // key half: keys [kh*1024, kh*1024+1024)
    const int m    = lane & 31;
    const int half = lane >> 5;
    const size_t kvbase = (size_t)bh * LL_ * DHEAD_;   // q,k: [bh][l][32]
    const size_t vbase  = (size_t)bh * DHEAD_ * LL_;   // v:   [bh][d][L]

    const int q0 = blockIdx.x * 128 + wq * 32;
    const int kb = kh * 1024;

    // persistent Q B-frags: B[k=d][n=q], d = half*8+j (+16)
    const v8s qf0 = *(const v8s*)(q + kvbase + (size_t)(q0 + m) * DHEAD_ + half * 8);
    const v8s qf1 = *(const v8s*)(q + kvbase + (size_t)(q0 + m) * DHEAD_ + 16 + half * 8);

    v16f O = {};
    float psum = 0.f;

    v8s kf0 = *(const v8s*)(k + kvbase + (size_t)(kb + m) * DHEAD_ + half * 8);
    v8s kf1 = *(const v8s*)(k + kvbase + (size_t)(kb + m) * DHEAD_ + 16 + half * 8);
    v8s vf0 = *(const v8s*)(v + vbase + (size_t)m * LL_ + kb + half * 8);
    v8s vf1 = *(const v8s*)(v + vbase + (size_t)m * LL_ + kb + 16 + half * 8);

    for (int kt = 0; kt < 1024; kt += 32) {
        // scores: S^T[key][q] = sum_d K[key][d] * Q[q][d]  (q pre-scaled by K1)
        v16f S = __builtin_amdgcn_mfma_f32_32x32x16_bf16(kf0, qf0, (v16f){}, 0, 0, 0);
        S      = __builtin_amdgcn_mfma_f32_32x32x16_bf16(kf1, qf1, S,        0, 0, 0);

        const int ktn = kb + ((kt + 32) & 1023);   // wrap within own half
        kf0 = *(const v8s*)(k + kvbase + (size_t)(ktn + m) * DHEAD_ + half * 8);
        kf1 = *(const v8s*)(k + kvbase + (size_t)(ktn + m) * DHEAD_ + 16 + half * 8);
        v8s vf0n = *(const v8s*)(v + vbase + (size_t)m * LL_ + ktn + half * 8);
        v8s vf1n = *(const v8s*)(v + vbase + (size_t)m * LL_ + ktn + 16 + half * 8);

        // p = exp2(S); pack key-pairs into dwords e0..e7 (bf16 half-up)
        unsigned e[8];
        #pragma unroll
        for (int i = 0; i < 8; ++i) {
            float pa = __builtin_amdgcn_exp2f(S[2 * i]);
            float pb = __builtin_amdgcn_exp2f(S[2 * i + 1]);
            psum += pa + pb;
            e[i] = __builtin_amdgcn_perm(fbits(pb) + 0x8000u, fbits(pa) + 0x8000u, 0x07060302u);
        }
        // C->A relayout: swap high-half(e_lo) with low-half(e_hi)
        v4u f1, f2;
#if __has_builtin(__builtin_amdgcn_permlane32_swap)
        {
            auto r02 = __builtin_amdgcn_permlane32_swap(e[0], e[2], false, false);
            auto r13 = __builtin_amdgcn_permlane32_swap(e[1], e[3], false, false);
            auto r46 = __builtin_amdgcn_permlane32_swap(e[4], e[6], false, false);
            auto r57 = __builtin_amdgcn_permlane32_swap(e[5], e[7], false, false);
            f1 = (v4u){r02[0], r13[0], r02[1], r13[1]};
            f2 = (v4u){r46[0], r57[0], r46[1], r57[1]};
        }
#else
        {
            unsigned o0 = __shfl_xor(e[0], 32, 64), o1 = __shfl_xor(e[1], 32, 64);
            unsigned o2 = __shfl_xor(e[2], 32, 64), o3 = __shfl_xor(e[3], 32, 64);
            unsigned o4 = __shfl_xor(e[4], 32, 64), o5 = __shfl_xor(e[5], 32, 64);
            unsigned o6 = __shfl_xor(e[6], 32, 64), o7 = __shfl_xor(e[7], 32, 64);
            f1 = half ? (v4u){o2, o3, e[2], e[3]} : (v4u){e[0], e[1], o0, o1};
            f2 = half ? (v4u){o6, o7, e[6], e[7]} : (v4u){e[4], e[5], o4, o5};
        }
#endif
        // PV: O[q][d] += P[q][key] * V[key][d]
        O = __builtin_amdgcn_mfma_f32_32x32x16_bf16(__builtin_bit_cast(v8s, f1), vf0, O, 0, 0, 0);
        O = __builtin_amdgcn_mfma_f32_32x32x16_bf16(__builtin_bit_cast(v8s, f2), vf1, O, 0, 0, 0);

        vf0 = vf0n; vf1 = vf1n;
    }

    // in-wave: combine lane-halves -> lane m holds den-partial for q = m
    psum += __shfl_xor(psum, 32, 64);

    // cross-wave combine of the two key-halves through LDS
    if (kh == 1) {
        #pragma unroll
        for (int r = 0; r < 16; ++r) {
            int qr = (r & 3) + 8 * (r >> 2) + 4 * half;
            Ost[wq][qr][m] = O[r];
        }
        if (half == 0) psumst[wq * 32 + m] = psum;
    }
    __syncthreads();
    if (kh == 0) {
        float den = psum + psumst[wq * 32 + m];
        float invden = 1.f / den;                    // lane m: 1/den(q=m)
        #pragma unroll
        for (int r = 0; r < 16; ++r) {
            int qr = (r & 3) + 8 * (r >> 2) + 4 * half;
            float inv = __shfl(invden, qr, 64);
            float val = (O[r] + Ost[wq][qr][m]) * inv;
            int row = q0 + qr;
            ao[((size_t)b * LL_ + row) * HID_ + h * DHEAD_ + m] = f2bf(val);
        }
    }
}

// ---------------------------------------------------------------------------
// Kernel 3: output projection via MFMA + bias + residual. 16-l blocks,
// wave = 16l x 64o slice (4 waves/SIMD occupancy). No LDS, no barriers.
// ---------------------------------------------------------------------------
__global__ __launch_bounds__(256) void k_oproj(
    const short* __restrict__ ao, const short* __restrict__ wo, const float* __restrict__ bo,
    const float* __restrict__ x, float* __restrict__ out)
{
    const int b = blockIdx.y;
    const int l0 = blockIdx.x * 16;
    const int tid = threadIdx.x;
    const int wave = tid >> 6, lane = tid & 63;
    const int n = lane & 15, quad = lane >> 4;

    v8s bf[4];
    #pragma unroll
    for (int ks = 0; ks < 4; ++ks)
        bf[ks] = *(const v8s*)(ao + ((size_t)b * LL_ + l0 + n) * HID_ + ks * 32 + quad * 8);

    #pragma unroll
    for (int oi_ = 0; oi_ < 4; ++oi_) {
        int ot = wave * 4 + oi_;
        v4f acc = {0.f, 0.f, 0.f, 0.f};
        #pragma unroll
        for (int ks = 0; ks < 4; ++ks) {
            const v8s af = *(const v8s*)(wo + (size_t)(ot * 16 + n) * HID_ + ks * 32 + quad * 8);
            acc = __builtin_amdgcn_mfma_f32_16x16x32_bf16(af, bf[ks], acc, 0, 0, 0);
        }
        #pragma unroll
        for (int r = 0; r < 4; ++r) {
            int o = ot * 16 + quad * 4 + r;
            size_t oi = ((size_t)b * CC_ + o) * LL_ + l0 + n;
            out[oi] = acc[r] + bo[o] + x[oi];
        }
    }
}

extern "C" void kernel_launch(void* const* d_in, const int* in_sizes, int n_in,
                              void* d_out, int out_size, void* d_ws, size_t ws_size,
                              hipStream_t stream) {
    const float* x  = (const float*)d_in[0];
    const float* g  = (const float*)d_in[1];
    const float* bv = (const float*)d_in[2];
    const float* Wq = (const float*)d_in[3];
    const float* Wk = (const float*)d_in[4];
    const float* Wv = (const float*)d_in[5];
    const float* Wo = (const float*)d_in[6];
    const float* bo = (const float*)d_in[7];
    float* out = (float*)d_out;

    const size_t qkv_elems = (size_t)BB_ * HEADS_ * LL_ * DHEAD_;
    short* q    = (short*)d_ws;
    short* k    = q + qkv_elems;
    short* v    = k + qkv_elems;
    short* ao   = v + qkv_elems;
    short* wqkv = ao + qkv_elems;
    short* wo   = wqkv + 384 * 256;

    k_prep  <<<dim3((384 * 256 + 256 * 128) / 256), dim3(256), 0, stream>>>(Wq, Wk, Wv, Wo, wqkv, wo);
    k_ln_qkv<<<dim3(LL_ / 32, BB_), dim3(512), 0, stream>>>(x, g, bv, wqkv, q, k, v);
    k_attn  <<<dim3(LL_ / 128, BB_ * HEADS_), dim3(512), 0, stream>>>(q, k, v, ao);
    k_oproj <<<dim3(LL_ / 16, BB_), dim3(256), 0, stream>>>(ao, wo, bo, x, out);
}